// Round 1
// baseline (89.281 us; speedup 1.0000x reference)
//
#include <hip/hip_runtime.h>

// MacaqueBrain: spikes,v_out = IF(v + outs@W + inject(x))
// N = 383*32 = 12256, W is [N,N] fp32 row-major (src-major), ain[t] = sum_s outs[s]*W[s*N+t]
#define N_NEURONS 12256
#define NV4       3064      // N/4 float4 per row
#define IN_LO     160       // IN_AREA*NSZ = 5*32
#define IN_HI     192
#define VTH       1.0f

__global__ __launch_bounds__(256) void mv_partial_kernel(
    const float*  __restrict__ outs,
    const float4* __restrict__ W4,
    float4*       __restrict__ partial4,
    int rows_per_chunk)
{
    __shared__ float s_outs[256];
    const int tid   = threadIdx.x;
    const int c4    = blockIdx.x * 256 + tid;   // float4 column index
    const int chunk = blockIdx.y;
    const bool active = (c4 < NV4);

    int r0 = chunk * rows_per_chunk;
    int r1 = r0 + rows_per_chunk;
    if (r1 > N_NEURONS) r1 = N_NEURONS;

    float4 acc = make_float4(0.f, 0.f, 0.f, 0.f);

    for (int rs = r0; rs < r1; rs += 256) {
        int cnt = r1 - rs;
        if (cnt > 256) cnt = 256;
        __syncthreads();
        if (tid < cnt) s_outs[tid] = outs[rs + tid];
        __syncthreads();

        for (int i = 0; i < cnt; ++i) {
            float o = s_outs[i];               // uniform across block -> uniform branch
            if (active && o != 0.0f) {
                float4 w = W4[(size_t)(rs + i) * NV4 + c4];
                acc.x = fmaf(o, w.x, acc.x);
                acc.y = fmaf(o, w.y, acc.y);
                acc.z = fmaf(o, w.z, acc.z);
                acc.w = fmaf(o, w.w, acc.w);
            }
        }
    }

    if (active) partial4[(size_t)chunk * NV4 + c4] = acc;
}

__global__ __launch_bounds__(256) void if_update_kernel(
    const float* __restrict__ partial,
    const float* __restrict__ x,
    const float* __restrict__ v,
    float*       __restrict__ out,
    int chunks)
{
    int col = blockIdx.x * 256 + threadIdx.x;
    if (col >= N_NEURONS) return;

    float s = 0.f;
    for (int ch = 0; ch < chunks; ++ch)
        s += partial[(size_t)ch * N_NEURONS + col];

    if (col >= IN_LO && col < IN_HI) s += x[col - IN_LO];

    float vn = v[col] + s;
    float sp = (vn >= VTH) ? 1.0f : 0.0f;
    out[col]             = sp;              // spikes
    out[N_NEURONS + col] = vn * (1.0f - sp); // v_out (hard reset)
}

extern "C" void kernel_launch(void* const* d_in, const int* in_sizes, int n_in,
                              void* d_out, int out_size, void* d_ws, size_t ws_size,
                              hipStream_t stream) {
    // setup_inputs order: x[32], outs[N], v[N], W[N*N]
    const float* x    = (const float*)d_in[0];
    const float* outs = (const float*)d_in[1];
    const float* v    = (const float*)d_in[2];
    const float* W    = (const float*)d_in[3];
    float* out = (float*)d_out;

    // Row-chunk count limited by workspace (one N-float partial vector per chunk).
    int max_chunks = (int)(ws_size / ((size_t)N_NEURONS * sizeof(float)));
    int chunks = max_chunks;
    if (chunks < 1)   chunks = 1;
    if (chunks > 128) chunks = 128;
    int rows_per_chunk = (N_NEURONS + chunks - 1) / chunks;
    chunks = (N_NEURONS + rows_per_chunk - 1) / rows_per_chunk;

    dim3 gridB((NV4 + 255) / 256, chunks);
    mv_partial_kernel<<<gridB, 256, 0, stream>>>(
        outs, (const float4*)W, (float4*)d_ws, rows_per_chunk);

    if_update_kernel<<<(N_NEURONS + 255) / 256, 256, 0, stream>>>(
        (const float*)d_ws, x, v, out, chunks);
}